// Round 1
// baseline (595.069 us; speedup 1.0000x reference)
//
#include <hip/hip_runtime.h>

#define NNODES 100000
#define F 256
#define NBKT ((NNODES + 127) / 128)    // 782 buckets of 128 src nodes
#define BKT_CAP 5120                   // mean 4092, +16 sigma; P(overflow) ~ 1e-13
#define CHUNK_A 8192                   // edges per bin_edges block

typedef unsigned short u16;
typedef unsigned int   u32;
typedef __attribute__((ext_vector_type(8))) short short8v;      // 8 bf16
typedef __attribute__((ext_vector_type(8))) unsigned short ushort8; // 8 bf16 bits
typedef __attribute__((ext_vector_type(4))) float f32x4;

__device__ __forceinline__ u16 f2bf(float f) {
    u32 u = __float_as_uint(f);
    u32 r = u + 0x7FFFu + ((u >> 16) & 1u);   // round-to-nearest-even
    return (u16)(r >> 16);
}
__device__ __forceinline__ float bf2f(u16 h) {
    return __uint_as_float(((u32)h) << 16);
}

// ---------------- cast W -> bf16 ----------------
__global__ __launch_bounds__(256) void cast_w(const float* __restrict__ W,
                                              u16* __restrict__ Wb) {
    int i = blockIdx.x * 256 + threadIdx.x;
    if (i >= F * F / 4) return;
    float4 w = ((const float4*)W)[i];
    ushort4 o;
    o.x = f2bf(w.x); o.y = f2bf(w.y); o.z = f2bf(w.z); o.w = f2bf(w.w);
    ((ushort4*)Wb)[i] = o;
}

// ---------------- cast X -> bf16 (streaming) ----------------
__global__ __launch_bounds__(256) void cast_x(const float* __restrict__ X,
                                              u16* __restrict__ Xb, int total4) {
    int i = blockIdx.x * 256 + threadIdx.x;
    if (i >= total4) return;
    float4 x = ((const float4*)X)[i];
    ushort4 o;
    o.x = f2bf(x.x); o.y = f2bf(x.y); o.z = f2bf(x.z); o.w = f2bf(x.w);
    ((ushort4*)Xb)[i] = o;
}

// ---------------- GEMM: Yb = bf16( Xb @ Wb^T ) via MFMA ----------------
// 128-col blocks (grid.y = 2): halves the Xb re-read vs 64-col blocks.
__global__ __launch_bounds__(256) void gemm_mfma(const u16* __restrict__ Xb,
                                                 const u16* __restrict__ Wb,
                                                 u16* __restrict__ Yb) {
    const int wave = threadIdx.x >> 6;
    const int lane = threadIdx.x & 63;
    const int lm   = lane & 15;
    const int kg   = lane >> 4;
    const int m0   = blockIdx.x * 128 + wave * 32;
    const int n0   = blockIdx.y * 128;

    f32x4 acc[2][8];
#pragma unroll
    for (int t = 0; t < 2; ++t)
#pragma unroll
        for (int u = 0; u < 8; ++u) acc[t][u] = (f32x4){0.f, 0.f, 0.f, 0.f};

    int rowA[2];
#pragma unroll
    for (int t = 0; t < 2; ++t) {
        int row = m0 + t * 16 + lm;
        rowA[t] = (row < NNODES) ? row : NNODES - 1;
    }

    for (int k0 = 0; k0 < F; k0 += 32) {
        const int kb = k0 + kg * 8;
        short8v aF[2];
#pragma unroll
        for (int t = 0; t < 2; ++t)
            aF[t] = *(const short8v*)(Xb + (size_t)rowA[t] * F + kb);
        short8v bF[8];
#pragma unroll
        for (int u = 0; u < 8; ++u)
            bF[u] = *(const short8v*)(Wb + (size_t)(n0 + u * 16 + lm) * F + kb);
#pragma unroll
        for (int t = 0; t < 2; ++t)
#pragma unroll
            for (int u = 0; u < 8; ++u)
                acc[t][u] = __builtin_amdgcn_mfma_f32_16x16x32_bf16(aF[t], bF[u], acc[t][u], 0, 0, 0);
    }

    // D layout (16x16x32): col = lane&15, row = (lane>>4)*4 + i
#pragma unroll
    for (int t = 0; t < 2; ++t) {
        int rbase = m0 + t * 16 + kg * 4;
#pragma unroll
        for (int i = 0; i < 4; ++i) {
            int row = rbase + i;
            if (row < NNODES) {
#pragma unroll
                for (int u = 0; u < 8; ++u)
                    Yb[(size_t)row * F + n0 + u * 16 + lm] = f2bf(acc[t][u][i]);
            }
        }
    }
}

// ---------------- init bucket cursors ----------------
__global__ __launch_bounds__(256) void init_cur(int* __restrict__ cur) {
    int i = blockIdx.x * 256 + threadIdx.x;
    if (i < NBKT) cur[i] = i * BKT_CAP;
}

// ---------------- Phase A: bin edges into 128-node buckets ----------------
// temp[pos] = ( (src&127)<<20 | dst , val_bits ), bucket-strided regions.
__global__ __launch_bounds__(256) void bin_edges(const int* __restrict__ src,
                                                 const int* __restrict__ dst,
                                                 const float* __restrict__ val,
                                                 int* __restrict__ cur,
                                                 int2* __restrict__ temp,
                                                 int n_edges) {
    __shared__ int hist[NBKT];
    __shared__ int bas[NBKT];
    const int e0 = blockIdx.x * CHUNK_A;
    for (int i = threadIdx.x; i < NBKT; i += 256) hist[i] = 0;
    __syncthreads();

    int lp[32];
#pragma unroll
    for (int k = 0; k < 32; ++k) {
        int e = e0 + k * 256 + threadIdx.x;
        if (e < n_edges) lp[k] = atomicAdd(&hist[src[e] >> 7], 1);
    }
    __syncthreads();
    for (int i = threadIdx.x; i < NBKT; i += 256) {
        int c = hist[i];
        bas[i] = c ? atomicAdd(&cur[i], c) : 0;
    }
    __syncthreads();
#pragma unroll
    for (int k = 0; k < 32; ++k) {
        int e = e0 + k * 256 + threadIdx.x;
        if (e < n_edges) {
            int s = src[e];
            int pos = bas[s >> 7] + lp[k];
            temp[pos] = make_int2(((s & 127) << 20) | dst[e], __float_as_int(val[e]));
        }
    }
}

// ---------------- Phase B: per-bucket node sort + nodeseg emit ----------------
__global__ __launch_bounds__(256) void sort_bucket(const int* __restrict__ cur,
                                                   const int2* __restrict__ temp,
                                                   int2* __restrict__ pack,
                                                   int2* __restrict__ nodeseg) {
    __shared__ int h[128];
    __shared__ int curl[128];
    const int b = blockIdx.x;
    const int base = b * BKT_CAP;
    const int cnt = cur[b] - base;
    const int tid = threadIdx.x;

    if (tid < 128) h[tid] = 0;
    __syncthreads();
    for (int j = tid; j < cnt; j += 256)
        atomicAdd(&h[temp[base + j].x >> 20], 1);
    __syncthreads();
    // inclusive scan over 128 entries
    for (int off = 1; off < 128; off <<= 1) {
        int x = 0;
        if (tid < 128 && tid >= off) x = h[tid - off];
        __syncthreads();
        if (tid < 128) h[tid] += x;
        __syncthreads();
    }
    if (tid < 128) {
        int incl = h[tid];
        int prev = tid ? h[tid - 1] : 0;
        curl[tid] = base + prev;
        int node = b * 128 + tid;
        if (node < NNODES) nodeseg[node] = make_int2(base + prev, base + incl);
    }
    __syncthreads();
    for (int j = tid; j < cnt; j += 256) {
        int2 p = temp[base + j];
        int loc = p.x >> 20;
        int pos = atomicAdd(&curl[loc], 1);
        pack[pos] = make_int2(p.x & 0xFFFFF, p.y);
    }
}

// ---------------- Gather: out[node] = b + sum val * Y[dst]  (bf16 Y) --------
// One wave per node. Lanes 0-31 handle even edges, 32-63 odd edges; each lane
// owns 8 feats (16 B loads). 16 edges per iteration => 8 outstanding Y-row
// loads per lane (MLP), ~2 dependent pack->Y rounds per mean-degree-32 node.
__global__ __launch_bounds__(256) void gather_nodes(const int2* __restrict__ nodeseg,
                                                    const int2* __restrict__ pack,
                                                    const u16* __restrict__ Yb,
                                                    const float* __restrict__ bias,
                                                    float* __restrict__ out) {
    int node = blockIdx.x * 4 + (threadIdx.x >> 6);
    if (node >= NNODES) return;
    const int lane = threadIdx.x & 63;
    const int half = lane >> 5;
    const int l5   = lane & 31;

    int2 seg = nodeseg[node];
    const int beg = seg.x, end = seg.y;

    float acc[8];
#pragma unroll
    for (int i = 0; i < 8; ++i) acc[i] = 0.f;

    for (int j = beg; j < end; j += 16) {     // 8 pairs = 16 edges per iter
        int dsts[8];
        float v[8];
        ushort8 y[8];
#pragma unroll
        for (int q = 0; q < 8; ++q) {
            int idx = j + 2 * q + half;
            int safe = idx < end ? idx : end - 1;
            long long raw = __builtin_nontemporal_load((const long long*)&pack[safe]);
            dsts[q] = (int)(raw & 0xFFFFFFFFll);
            v[q] = (idx < end) ? __int_as_float((int)(raw >> 32)) : 0.f;
        }
#pragma unroll
        for (int q = 0; q < 8; ++q)
            y[q] = *(const ushort8*)(Yb + (size_t)dsts[q] * F + l5 * 8);
#pragma unroll
        for (int q = 0; q < 8; ++q)
#pragma unroll
            for (int i = 0; i < 8; ++i)
                acc[i] += v[q] * bf2f(y[q][i]);
    }

    // combine halves
#pragma unroll
    for (int i = 0; i < 8; ++i) acc[i] += __shfl_xor(acc[i], 32);

    // bias + store: lane writes feats [l5*8 + half*4 .. +3]
    const int col = l5 * 8 + half * 4;
    float4 bv = *(const float4*)&bias[col];
    f32x4 o;
    o[0] = acc[half * 4 + 0] + bv.x;
    o[1] = acc[half * 4 + 1] + bv.y;
    o[2] = acc[half * 4 + 2] + bv.z;
    o[3] = acc[half * 4 + 3] + bv.w;
    __builtin_nontemporal_store(o, (f32x4*)&out[(size_t)node * F + col]);
}

extern "C" void kernel_launch(void* const* d_in, const int* in_sizes, int n_in,
                              void* d_out, int out_size, void* d_ws, size_t ws_size,
                              hipStream_t stream) {
    const float* X        = (const float*)d_in[0];
    const int*   edge_src = (const int*)d_in[1];
    const int*   edge_dst = (const int*)d_in[2];
    const float* edge_val = (const float*)d_in[3];
    const float* W        = (const float*)d_in[4];
    const float* b        = (const float*)d_in[5];
    float*       out      = (float*)d_out;
    const int n_edges     = in_sizes[1];

    // Workspace (~116.2 MB). Xb (51.2 MB) overlays pack+temp (64.1 MB):
    // Xb is dead after gemm; temp/pack are written only after gemm.
    char* base = (char*)d_ws;
    const size_t ybBytes   = (size_t)NNODES * F * sizeof(u16);        // 51.2 MB
    const size_t packBytes = (size_t)NBKT * BKT_CAP * sizeof(int2);   // 32.03 MB
    u16*  Yb      = (u16*)base;
    int2* pack    = (int2*)(base + ybBytes);
    int2* temp    = (int2*)(base + ybBytes + packBytes);
    u16*  Xb      = (u16*)pack;                                       // overlay
    u16*  Wb      = (u16*)(base + ybBytes + 2 * packBytes);
    int2* nodeseg = (int2*)((char*)Wb + (size_t)F * F * sizeof(u16));
    int*  cur     = (int*)(nodeseg + NNODES);

    // 1) casts
    cast_w<<<(F * F / 4 + 255) / 256, 256, 0, stream>>>(W, Wb);
    int xt4 = NNODES * F / 4;
    cast_x<<<(xt4 + 255) / 256, 256, 0, stream>>>(X, Xb, xt4);

    // 2) Yb = bf16(Xb @ Wb^T) via MFMA
    dim3 ggrid((NNODES + 127) / 128, F / 128);
    gemm_mfma<<<ggrid, 256, 0, stream>>>(Xb, Wb, Yb);

    // 3) bucket cursors + two-phase binned counting sort (no global scan)
    init_cur<<<(NBKT + 255) / 256, 256, 0, stream>>>(cur);
    bin_edges<<<(n_edges + CHUNK_A - 1) / CHUNK_A, 256, 0, stream>>>(edge_src, edge_dst, edge_val,
                                                                     cur, temp, n_edges);
    sort_bucket<<<NBKT, 256, 0, stream>>>(cur, temp, pack, nodeseg);

    // 4) Gather + bias
    gather_nodes<<<(NNODES + 3) / 4, 256, 0, stream>>>(nodeseg, pack, Yb, b, out);
}